// Round 10
// baseline (293.181 us; speedup 1.0000x reference)
//
#include <hip/hip_runtime.h>

#define F_IN 128
#define F_OUT 64
#define LSTR 136
#define Q16 65536.0f
#define NPASS 8

typedef __bf16 bf16x8 __attribute__((ext_vector_type(8)));
typedef float f32x4 __attribute__((ext_vector_type(4)));

__device__ inline ushort f2bf(float f) {
    unsigned u = __float_as_uint(f);
    return (ushort)((u + 0x7fff + ((u >> 16) & 1)) >> 16);
}
__device__ inline float bf2f(ushort u) { return __uint_as_float((unsigned)u << 16); }

// ---- mega: blocks [0,nb_edge): ONE u32 atomic per edge:
//      packed[c] += (1<<24) | Q16(ew); old>>24 = rank.
//      rank word also carries bf15(ew) so k_place never reloads ew.
//      blocks [nb_edge,...): bf16 MFMA GEMM (xwb = bf16(X@W)) hidden under it ----
__global__ __launch_bounds__(256, 8) void k_mega(
        const float* __restrict__ X, const float* __restrict__ W,
        const int* __restrict__ colp, const float* __restrict__ ew,
        unsigned* __restrict__ packed, unsigned* __restrict__ rank,
        ushort* __restrict__ xwb, int n, int e, int nb_edge) {
    __shared__ ushort Wt[64 * LSTR];
    const int t = threadIdx.x;

    if ((int)blockIdx.x < nb_edge) {
        int i = (int)blockIdx.x * 256 + t;
        if (i < e) {
            int c = colp[i];
            float w = ew[i];
            unsigned add = (1u << 24) + __float2uint_rn(w * Q16);
            unsigned old = atomicAdd(&packed[c], add);
            unsigned u = __float_as_uint(w);
            unsigned nb15 = ((u + 0x7fff + ((u >> 16) & 1)) >> 16) & 0x7fffu;
            rank[i] = ((old >> 24) << 15) | nb15;  // coalesced
        }
        return;
    }

    // ---- GEMM: 64 rows x 64 cols, K=128, mfma_f32_16x16x32_bf16 ----
    const int row0 = ((int)blockIdx.x - nb_edge) * 64;
    const float4* W4 = (const float4*)W;
    #pragma unroll
    for (int i = 0; i < 8; ++i) {
        int idx = t + i * 256;  // 2048 float4s = 128x64 W
        float4 v = W4[idx];
        int flat = idx * 4;
        int k = flat >> 6, c = flat & 63;
        Wt[(c + 0) * LSTR + k] = f2bf(v.x);
        Wt[(c + 1) * LSTR + k] = f2bf(v.y);
        Wt[(c + 2) * LSTR + k] = f2bf(v.z);
        Wt[(c + 3) * LSTR + k] = f2bf(v.w);
    }
    const int lane = t & 63, wv_ = t >> 6;
    const int m16 = lane & 15, quad = lane >> 4;
    int arow = row0 + wv_ * 16 + m16;
    if (arow >= n) arow = n - 1;  // clamp; store is guarded
    const float* xr = X + (long)arow * F_IN;
    __syncthreads();

    f32x4 acc[4] = {{0,0,0,0},{0,0,0,0},{0,0,0,0},{0,0,0,0}};
    #pragma unroll
    for (int kk = 0; kk < 4; ++kk) {
        float4 xa = *(const float4*)(xr + kk * 32 + quad * 8);
        float4 xb = *(const float4*)(xr + kk * 32 + quad * 8 + 4);
        union { ushort us[8]; bf16x8 v; } ua;
        ua.us[0] = f2bf(xa.x); ua.us[1] = f2bf(xa.y);
        ua.us[2] = f2bf(xa.z); ua.us[3] = f2bf(xa.w);
        ua.us[4] = f2bf(xb.x); ua.us[5] = f2bf(xb.y);
        ua.us[6] = f2bf(xb.z); ua.us[7] = f2bf(xb.w);
        #pragma unroll
        for (int nt = 0; nt < 4; ++nt) {
            bf16x8 bb = *(const bf16x8*)&Wt[(nt * 16 + m16) * LSTR + kk * 32 + quad * 8];
            acc[nt] = __builtin_amdgcn_mfma_f32_16x16x32_bf16(ua.v, bb, acc[nt], 0, 0, 0);
        }
    }
    #pragma unroll
    for (int nt = 0; nt < 4; ++nt) {
        #pragma unroll
        for (int reg = 0; reg < 4; ++reg) {
            int gr = row0 + wv_ * 16 + quad * 4 + reg;  // C/D: row=quad*4+reg
            if (gr < n) xwb[(long)gr * F_OUT + nt * 16 + m16] = f2bf(acc[nt][reg]);
        }
    }
}

// ---- scan1: per-1024-node exclusive scan of counts + decoupled lookback ----
__global__ __launch_bounds__(256) void k_scan1(
        const unsigned* __restrict__ packed, int* __restrict__ loffs,
        int* __restrict__ gpart, int n, int nbp) {
    __shared__ int sdata[256];
    const int t = threadIdx.x, bk = blockIdx.x;
    const int base = bk * 1024 + t * 4;
    int h[4];
    #pragma unroll
    for (int q = 0; q < 4; ++q)
        h[q] = (base + q < n) ? (int)(packed[base + q] >> 24) : 0;
    int tot = h[0] + h[1] + h[2] + h[3];
    sdata[t] = tot;
    __syncthreads();
    for (int off = 1; off < 256; off <<= 1) {
        int v = (t >= off) ? sdata[t - off] : 0;
        __syncthreads();
        sdata[t] += v;
        __syncthreads();
    }
    int excl = sdata[t] - tot;
    if (base + 0 < n) loffs[base + 0] = excl;
    if (base + 1 < n) loffs[base + 1] = excl + h[0];
    if (base + 2 < n) loffs[base + 2] = excl + h[0] + h[1];
    if (base + 3 < n) loffs[base + 3] = excl + h[0] + h[1] + h[2];
    int T = sdata[255];
    int j = bk + 1 + t;
    if (j < nbp) atomicAdd(&gpart[j], T);
}

// ---- place: 8 col-range passes so the edata scatter window is ~3.2MB/pass
//      (L2-resident; each 64B line fully assembled before writeback).
//      edata[csr_pos] = row<<15 | bf15(ew * dis[row]) ----
__global__ __launch_bounds__(256) void k_place(
        const int* __restrict__ ei, const unsigned* __restrict__ rank,
        const int* __restrict__ loffs, const int* __restrict__ gpart,
        const unsigned* __restrict__ packed, unsigned* __restrict__ edata,
        int e, int seg) {
    int i = (int)blockIdx.x * 256 + threadIdx.x;
    if (i >= e) return;
    int col = ei[e + i];
    int pass_of_col = col / seg;
    for (int pass = 0; pass < NPASS; ++pass) {
        if (pass_of_col == pass) {
            int row = ei[i];
            unsigned rk = rank[i];
            unsigned pk = packed[row];  // random 4B load; 400KB, L2-hot
            float dr = rsqrtf((float)(pk & 0xffffffu) * (1.0f / Q16) + 1.0f);
            float wn = __uint_as_float((rk & 0x7fffu) << 16) * dr;  // ew * dis[row]
            unsigned u = __float_as_uint(wn);
            unsigned nb15 = ((u + 0x7fff + ((u >> 16) & 1)) >> 16) & 0x7fffu;
            int pos = loffs[col] + gpart[col >> 10] + (int)(rk >> 15);
            __builtin_nontemporal_store(((unsigned)row << 15) | nb15, &edata[pos]);
        }
        __builtin_amdgcn_s_barrier();  // keep block's passes in lockstep
    }
}

// ---- gather: wave per node; QUARTER-wave (16 lanes) per edge stream;
//      lane fl handles features 4fl..4fl+3. out = dc*(dc*xw[n] + sum wn*xw[r]) + b ----
__global__ __launch_bounds__(256, 8) void k_gather(
        const unsigned* __restrict__ packed, const int* __restrict__ loffs,
        const int* __restrict__ gpart, const unsigned* __restrict__ edata,
        const ushort* __restrict__ xwb, const float* __restrict__ b,
        float* __restrict__ out, int n) {
    int node = (int)blockIdx.x * 4 + (threadIdx.x >> 6);
    if (node >= n) return;
    int lane = threadIdx.x & 63, q = lane >> 4, fl = lane & 15;
    unsigned pk = packed[node];
    int count = (int)(pk >> 24);
    float dc = rsqrtf((float)(pk & 0xffffffu) * (1.0f / Q16) + 1.0f);
    int beg = loffs[node] + gpart[node >> 10];
    int end = beg + count;
    float a0 = 0.f, a1 = 0.f, a2 = 0.f, a3 = 0.f;
    if (q == 0) {  // self-loop term: dc*xw here, final *dc => dc^2*xw
        ushort4 xv = *(const ushort4*)(xwb + (long)node * 64 + fl * 4);
        a0 = dc * bf2f(xv.x); a1 = dc * bf2f(xv.y);
        a2 = dc * bf2f(xv.z); a3 = dc * bf2f(xv.w);
    }
    int j = beg + q;
    for (; j + 12 < end; j += 16) {  // 4 edges per quarter in flight
        unsigned v0 = __builtin_nontemporal_load(&edata[j]);
        unsigned v1 = __builtin_nontemporal_load(&edata[j + 4]);
        unsigned v2 = __builtin_nontemporal_load(&edata[j + 8]);
        unsigned v3 = __builtin_nontemporal_load(&edata[j + 12]);
        ushort4 x0 = *(const ushort4*)(xwb + (long)(v0 >> 15) * 64 + fl * 4);
        ushort4 x1 = *(const ushort4*)(xwb + (long)(v1 >> 15) * 64 + fl * 4);
        ushort4 x2 = *(const ushort4*)(xwb + (long)(v2 >> 15) * 64 + fl * 4);
        ushort4 x3 = *(const ushort4*)(xwb + (long)(v3 >> 15) * 64 + fl * 4);
        float w0 = __uint_as_float((v0 & 0x7fffu) << 16);
        float w1 = __uint_as_float((v1 & 0x7fffu) << 16);
        float w2 = __uint_as_float((v2 & 0x7fffu) << 16);
        float w3 = __uint_as_float((v3 & 0x7fffu) << 16);
        a0 += w0 * bf2f(x0.x) + w1 * bf2f(x1.x) + w2 * bf2f(x2.x) + w3 * bf2f(x3.x);
        a1 += w0 * bf2f(x0.y) + w1 * bf2f(x1.y) + w2 * bf2f(x2.y) + w3 * bf2f(x3.y);
        a2 += w0 * bf2f(x0.z) + w1 * bf2f(x1.z) + w2 * bf2f(x2.z) + w3 * bf2f(x3.z);
        a3 += w0 * bf2f(x0.w) + w1 * bf2f(x1.w) + w2 * bf2f(x2.w) + w3 * bf2f(x3.w);
    }
    for (; j < end; j += 4) {
        unsigned v = __builtin_nontemporal_load(&edata[j]);
        float w = __uint_as_float((v & 0x7fffu) << 16);
        ushort4 x = *(const ushort4*)(xwb + (long)(v >> 15) * 64 + fl * 4);
        a0 += w * bf2f(x.x); a1 += w * bf2f(x.y);
        a2 += w * bf2f(x.z); a3 += w * bf2f(x.w);
    }
    a0 += __shfl_xor(a0, 16); a0 += __shfl_xor(a0, 32);
    a1 += __shfl_xor(a1, 16); a1 += __shfl_xor(a1, 32);
    a2 += __shfl_xor(a2, 16); a2 += __shfl_xor(a2, 32);
    a3 += __shfl_xor(a3, 16); a3 += __shfl_xor(a3, 32);
    if (q == 0) {
        float4 bb = ((const float4*)b)[fl];
        float f0 = dc * a0 + bb.x, f1 = dc * a1 + bb.y;
        float f2 = dc * a2 + bb.z, f3 = dc * a3 + bb.w;
        f32x4 r = { f0 > 0.f ? f0 : 0.f, f1 > 0.f ? f1 : 0.f,
                    f2 > 0.f ? f2 : 0.f, f3 > 0.f ? f3 : 0.f };
        __builtin_nontemporal_store(r, &((f32x4*)out)[(long)node * 16 + fl]);
    }
}

extern "C" void kernel_launch(void* const* d_in, const int* in_sizes, int n_in,
                              void* d_out, int out_size, void* d_ws, size_t ws_size,
                              hipStream_t stream) {
    const float* X  = (const float*)d_in[0];
    const int*   ei = (const int*)d_in[1];
    const float* ew = (const float*)d_in[2];
    const float* W  = (const float*)d_in[3];
    const float* b  = (const float*)d_in[4];
    float* out = (float*)d_out;

    const int n = in_sizes[0] / F_IN;   // 100000
    const int e = in_sizes[2];          // 1600000

    long p = 0;
    auto alloc = [&](long bytes) { long off = p; p += (bytes + 255) & ~255L; return off; };
    char* ws = (char*)d_ws;
    long o_packed = alloc((long)n * 4);   // zeroed (with gpart) by memset
    long o_gpart  = alloc(1024);
    long o_zend   = o_gpart + 1024;
    long o_rank   = alloc((long)e * 4);
    long o_loffs  = alloc((long)n * 4);
    long o_edata  = alloc((long)e * 4);
    long o_xwb    = alloc((long)n * F_OUT * 2);
    unsigned* packed = (unsigned*)(ws + o_packed);
    int*      gpart  = (int*)     (ws + o_gpart);
    unsigned* rank   = (unsigned*)(ws + o_rank);
    int*      loffs  = (int*)     (ws + o_loffs);
    unsigned* edata  = (unsigned*)(ws + o_edata);
    ushort*   xwb    = (ushort*)  (ws + o_xwb);

    const int nb_edge = (e + 255) / 256;
    const int nb_gemm = (n + 63) / 64;
    const int nbp     = (n + 1023) / 1024;  // 98
    const int seg     = (n + NPASS - 1) / NPASS;  // 12500

    (void)hipMemsetAsync(ws, 0, (size_t)o_zend, stream);  // packed + gpart
    k_mega<<<nb_edge + nb_gemm, 256, 0, stream>>>(X, W, ei + e, ew, packed, rank,
                                                  xwb, n, e, nb_edge);
    k_scan1<<<nbp, 256, 0, stream>>>(packed, loffs, gpart, n, nbp);
    k_place<<<nb_edge, 256, 0, stream>>>(ei, rank, loffs, gpart, packed, edata, e, seg);
    k_gather<<<(n + 3) / 4, 256, 0, stream>>>(packed, loffs, gpart, edata, xwb, b, out, n);
}